// Round 10
// baseline (104.860 us; speedup 1.0000x reference)
//
#include <hip/hip_runtime.h>

// ---------------------------------------------------------------------------
// GCNN Double-Q critic, MI355X (gfx950) — round 10.
// Structure: A symmetric => transpose-free MFMA chain (D-frag == next A-frag).
// Round 10: (1) layer-2 z stored as SINGLE RN bf16 (W1 already single) =>
// 1 MFMA per (net,q,t) per batch; (2) TWO batches per wave => each W ds_read
// and W0F load amortized over 2 batches. 4-wave blocks, 8 batches/block,
// grid 512, 2 blocks/CU. Split precision kept in z0/L1/mix operands.
// ---------------------------------------------------------------------------

typedef short    s16x8 __attribute__((ext_vector_type(8)));
typedef float    f32x4 __attribute__((ext_vector_type(4)));
typedef unsigned u32x4 __attribute__((ext_vector_type(4)));

#define MFMA32(a, b, c) __builtin_amdgcn_mfma_f32_16x16x32_bf16((a), (b), (c), 0, 0, 0)

// d_ws layout (units: shorts)
constexpr int WS_W0F = 0;       // [net][t=8][lane=64][8] : {h0..h3,l0..l3}
constexpr int WS_W1  = 8192;    // [net][q=4][t=8][lane=64][8] bf16 RN

// dynamic LDS: [0,64KB) W1 frags (both nets), [64KB,+6.4KB) RAW (8 x 200 f32)
constexpr int LDS_RAW    = 65536;
constexpr int SMEM_TOTAL = 65536 + 8 * 200 * 4;  // 71936

__device__ __forceinline__ unsigned short bf16_rn(float f) {
  unsigned u = __float_as_uint(f);
  u = u + 0x7FFFu + ((u >> 16) & 1u);
  return (unsigned short)(u >> 16);
}
__device__ __forceinline__ void split2(float f, unsigned short& h, unsigned short& l) {
  h = bf16_rn(f);
  float fh = __uint_as_float(((unsigned)h) << 16);
  l = bf16_rn(f - fh);
}
// Packed split of a pair: H = {bf16_rhu(f1), bf16_rhu(f0)}, L = truncated
// residuals. 8 VALU per pair.
__device__ __forceinline__ void split_pk(float f0, float f1,
                                         unsigned& H, unsigned& L) {
  unsigned u0 = __float_as_uint(f0) + 0x8000u;
  unsigned u1 = __float_as_uint(f1) + 0x8000u;
  H = __builtin_amdgcn_perm(u1, u0, 0x07060302u);
  float r0 = f0 - __uint_as_float(u0 & 0xFFFF0000u);
  float r1 = f1 - __uint_as_float(u1 & 0xFFFF0000u);
  L = __builtin_amdgcn_perm(__float_as_uint(r1), __float_as_uint(r0), 0x07060302u);
}
// Packed single RN(~RHU) bf16 pair, no residual. 3 VALU per pair.
__device__ __forceinline__ unsigned pack_hi(float f0, float f1) {
  return __builtin_amdgcn_perm(__float_as_uint(f1) + 0x8000u,
                               __float_as_uint(f0) + 0x8000u, 0x07060302u);
}
__device__ __forceinline__ s16x8 as_s16x8(u32x4 v) {
  return __builtin_bit_cast(s16x8, v);
}

// ---------------------------- prep kernel ----------------------------------
extern "C" __global__ void __launch_bounds__(256)
prep_weights(const float* __restrict__ w0a, const float* __restrict__ w1a,
             const float* __restrict__ w0b, const float* __restrict__ w1b,
             unsigned short* __restrict__ ws) {
  const int tid = threadIdx.x;
  if (blockIdx.x < 16) {
    // W1 fragments (single bf16 RN): one 8-elem frag per thread.
    int f = blockIdx.x * 256 + tid;          // 0..4095
    int lane = f & 63, t = (f >> 6) & 7, q = (f >> 9) & 3, net = f >> 11;
    const float* W1 = net ? w1b : w1a;
    int c = 16 * t + (lane & 15);
    int kbase = 32 * q + 4 * (lane >> 4);
    s16x8 v;
#pragma unroll
    for (int e = 0; e < 8; ++e) {
      int k = kbase + (e & 3) + 16 * (e >> 2);
      v[e] = (short)bf16_rn(W1[k * 128 + c]);
    }
    ((s16x8*)(ws + WS_W1))[((net * 4 + q) * 8 + t) * 64 + lane] = v;
  } else {
    // W0 fragments hi/lo (K padded 10->16 with zeros): 1024 frags, 4/thread
#pragma unroll
    for (int i = 0; i < 4; ++i) {
      int f = i * 256 + tid;                 // 0..1023
      int lane = f & 63, t = (f >> 6) & 7, net = (f >> 9) & 1;
      const float* W0 = net ? w0b : w0a;
      int c = 16 * t + (lane & 15);
      int kbase = 4 * (lane >> 4);
      s16x8 v;
#pragma unroll
      for (int j = 0; j < 4; ++j) {
        int k = kbase + j;
        float w = (k < 10) ? W0[k * 128 + c] : 0.f;
        unsigned short h, l; split2(w, h, l);
        v[j] = (short)h; v[4 + j] = (short)l;
      }
      ((s16x8*)(ws + WS_W0F))[(net * 8 + t) * 64 + lane] = v;
    }
  }
}

// ---------------------------- main kernel ----------------------------------
extern "C" __global__ void __launch_bounds__(256, 2)
gcnn_critic_kernel(const float* __restrict__ obs, const float* __restrict__ act,
                   const float* __restrict__ b0a, const float* __restrict__ b1a,
                   const float* __restrict__ w2a, const float* __restrict__ b2a,
                   const float* __restrict__ b0b, const float* __restrict__ b1b,
                   const float* __restrict__ w2b, const float* __restrict__ b2b,
                   const unsigned short* __restrict__ ws,
                   float* __restrict__ out) {
  extern __shared__ char smem[];
  const int tid  = threadIdx.x;
  const int lane = tid & 63;
  const int wv   = tid >> 6;            // 0..3
  const int l15  = lane & 15;
  const int lg   = lane >> 4;
  const int bb   = blockIdx.x * 8 + wv * 2;  // two batches per wave

  s16x8* lW  = (s16x8*)smem;                 // 4096 fragments (64KB)
  float* raw = (float*)(smem + LDS_RAW) + wv * 400;  // 2 x 200 floats

  // ---- cooperative stage: BOTH nets' W1 fragments into LDS (64KB) ----
  {
    const s16x8* gW = (const s16x8*)(ws + WS_W1);
#pragma unroll
    for (int k = 0; k < 16; ++k) lW[tid + k * 256] = gW[tid + k * 256];
  }
  // stage raw features for both batches: [0..159]=obs, [160..191]=action
#pragma unroll
  for (int i = 0; i < 6; ++i) {
    int idx = i * 64 + lane;             // 0..383
    int bi = (idx >= 192) ? 1 : 0;
    int j = idx - bi * 192;
    float v = (j < 160) ? obs[(bb + bi) * 160 + j] : act[(bb + bi) * 32 + (j - 160)];
    raw[bi * 200 + j] = v;
  }
  __syncthreads();

  // ---- per-batch setup: adjacency + x fragment + z0 ----
  float Af[2][4];
  s16x8 ABh[2], ABl[2], z0op[2];
#pragma unroll
  for (int bi = 0; bi < 2; ++bi) {
    const float* rb = raw + bi * 200;
    float wreg[4];
    float wsum = 0.f;
#pragma unroll
    for (int j = 0; j < 4; ++j) {
      int s = 4 * lg + j;
      float dx = rb[l15 * 10]     - rb[s * 10];
      float dy = rb[l15 * 10 + 1] - rb[s * 10 + 1];
      float w = expf(-sqrtf(dx * dx + dy * dy));
      wreg[j] = w;
      wsum += w;
    }
    wsum += __shfl_xor(wsum, 16, 64);
    wsum += __shfl_xor(wsum, 32, 64);        // deg[d=l15]
    float dv = 1.0f / sqrtf(wsum);
#pragma unroll
    for (int j = 0; j < 4; ++j) {
      float dvs = __shfl(dv, 4 * lg + j, 64);
      Af[bi][j] = wreg[j] * dv * dvs;
    }
    unsigned AH01, AL01, AH23, AL23;
    split_pk(Af[bi][0], Af[bi][1], AH01, AL01);
    split_pk(Af[bi][2], Af[bi][3], AH23, AL23);
    ABh[bi] = as_s16x8((u32x4){AH01, AH23, AH01, AH23});
    ABl[bi] = as_s16x8((u32x4){AL01, AL23, 0u, 0u});

    float xv[4];
#pragma unroll
    for (int j = 0; j < 4; ++j) {
      int s = 4 * lg + j;
      float v = 0.f;
      if (l15 < 8)       v = rb[s * 10 + 2 + l15];
      else if (l15 < 10) v = rb[160 + s * 2 + (l15 - 8)];
      xv[j] = v;
    }
    unsigned xH0, xL0, xH1, xL1;
    split_pk(xv[0], xv[1], xH0, xL0);
    split_pk(xv[2], xv[3], xH1, xL1);
    s16x8 xop = as_s16x8((u32x4){xH0, xH1, xL0, xL1});

    f32x4 z0 = {0.f, 0.f, 0.f, 0.f};
    z0 = MFMA32(xop, ABh[bi], z0);
    z0 = MFMA32(xop, ABl[bi], z0);
    unsigned zH0, zL0, zH1, zL1;
    split_pk(z0[0], z0[1], zH0, zL0);
    split_pk(z0[2], z0[3], zH1, zL1);
    z0op[bi] = as_s16x8((u32x4){zH0, zH1, zL0, zL1});
  }

  const s16x8* W0F = (const s16x8*)(ws + WS_W0F);
  const s16x8 zero8 = {0, 0, 0, 0, 0, 0, 0, 0};
  float b2v0 = b2a[0], b2v1 = b2b[0];

#pragma unroll 1
  for (int net = 0; net < 2; ++net) {
    const float* B0 = net ? b0b : b0a;
    const float* B1 = net ? b1b : b1a;
    const float* W2 = net ? w2b : w2a;
    const float b2v = net ? b2v1 : b2v0;

    // ---- layer 1: h1 = relu(z0@W0 + b0); W0F load shared by both batches --
    s16x8 h1op[2][8];
#pragma unroll
    for (int t = 0; t < 8; ++t) {
      s16x8 wf = W0F[(net * 8 + t) * 64 + lane];
      s16x8 Bh = __builtin_shufflevector(wf, wf, 0, 1, 2, 3, 0, 1, 2, 3);
      s16x8 Bl = __builtin_shufflevector(wf, zero8, 4, 5, 6, 7, 8, 9, 10, 11);
      float bv = B0[16 * t + l15];
#pragma unroll
      for (int bi = 0; bi < 2; ++bi) {
        f32x4 a = {0.f, 0.f, 0.f, 0.f};
        a = MFMA32(z0op[bi], Bh, a);
        a = MFMA32(z0op[bi], Bl, a);
        float a0 = fmaxf(a[0] + bv, 0.f), a1 = fmaxf(a[1] + bv, 0.f);
        float a2 = fmaxf(a[2] + bv, 0.f), a3 = fmaxf(a[3] + bv, 0.f);
        unsigned H0, L0, H1, L1;
        split_pk(a0, a1, H0, L0);
        split_pk(a2, a3, H1, L1);
        h1op[bi][t] = as_s16x8((u32x4){H0, H1, L0, L1});
      }
    }

    // ---- mix: z1^T = h1^T @ A ; output packed SINGLE RN bf16 ----
    unsigned zHw[2][8][2];
#pragma unroll
    for (int t = 0; t < 8; ++t)
#pragma unroll
      for (int bi = 0; bi < 2; ++bi) {
        f32x4 z = {0.f, 0.f, 0.f, 0.f};
        z = MFMA32(h1op[bi][t], ABh[bi], z);
        z = MFMA32(h1op[bi][t], ABl[bi], z);
        zHw[bi][t][0] = pack_hi(z[0], z[1]);
        zHw[bi][t][1] = pack_hi(z[2], z[3]);
      }

    // ---- layer 2: h2 = relu(z1@W1 + b1); z single x W single, 2 batches --
    f32x4 acc[2][8];
#pragma unroll
    for (int bi = 0; bi < 2; ++bi)
#pragma unroll
      for (int t = 0; t < 8; ++t) acc[bi][t] = (f32x4){0.f, 0.f, 0.f, 0.f};
    __builtin_amdgcn_s_setprio(1);
#pragma unroll
    for (int q = 0; q < 4; ++q) {
      s16x8 zA = as_s16x8((u32x4){zHw[0][2 * q][0], zHw[0][2 * q][1],
                                  zHw[0][2 * q + 1][0], zHw[0][2 * q + 1][1]});
      s16x8 zB = as_s16x8((u32x4){zHw[1][2 * q][0], zHw[1][2 * q][1],
                                  zHw[1][2 * q + 1][0], zHw[1][2 * q + 1][1]});
      int base = (net * 4 + q) * 8 * 64 + lane;
#pragma unroll
      for (int t = 0; t < 8; ++t) {
        s16x8 W = lW[base + t * 64];
        acc[0][t] = MFMA32(zA, W, acc[0][t]);
        acc[1][t] = MFMA32(zB, W, acc[1][t]);
      }
    }
    __builtin_amdgcn_s_setprio(0);

    // ---- layer 3: s[node] = sum_c relu(h2+b1)*W2 ; q = A@s + b2 ----
    float part[2][4] = {{0.f, 0.f, 0.f, 0.f}, {0.f, 0.f, 0.f, 0.f}};
#pragma unroll
    for (int t = 0; t < 8; ++t) {
      float bv  = B1[16 * t + l15];
      float wv2 = W2[16 * t + l15];
#pragma unroll
      for (int bi = 0; bi < 2; ++bi)
#pragma unroll
        for (int r = 0; r < 4; ++r)
          part[bi][r] += fmaxf(acc[bi][t][r] + bv, 0.f) * wv2;
    }
#pragma unroll
    for (int d = 1; d < 16; d <<= 1)
#pragma unroll
      for (int bi = 0; bi < 2; ++bi)
#pragma unroll
        for (int r = 0; r < 4; ++r)
          part[bi][r] += __shfl_xor(part[bi][r], d, 64);
#pragma unroll
    for (int bi = 0; bi < 2; ++bi) {
      float pq = Af[bi][0] * part[bi][0] + Af[bi][1] * part[bi][1] +
                 Af[bi][2] * part[bi][2] + Af[bi][3] * part[bi][3];
      pq += __shfl_xor(pq, 16, 64);
      pq += __shfl_xor(pq, 32, 64);
      if (lane < 16)
        out[net * 65536 + (bb + bi) * 16 + l15] = pq + b2v;
    }
  }
}

extern "C" void kernel_launch(void* const* d_in, const int* in_sizes, int n_in,
                              void* d_out, int out_size, void* d_ws, size_t ws_size,
                              hipStream_t stream) {
  (void)in_sizes; (void)n_in; (void)out_size; (void)ws_size;
  const float* obs = (const float*)d_in[0];
  const float* act = (const float*)d_in[1];
  const float* w0a = (const float*)d_in[2];
  const float* b0a = (const float*)d_in[3];
  const float* w1a = (const float*)d_in[4];
  const float* b1a = (const float*)d_in[5];
  const float* w2a = (const float*)d_in[6];
  const float* b2a = (const float*)d_in[7];
  const float* w0b = (const float*)d_in[8];
  const float* b0b = (const float*)d_in[9];
  const float* w1b = (const float*)d_in[10];
  const float* b1b = (const float*)d_in[11];
  const float* w2b = (const float*)d_in[12];
  const float* b2b = (const float*)d_in[13];
  unsigned short* ws = (unsigned short*)d_ws;

  prep_weights<<<17, 256, 0, stream>>>(w0a, w1a, w0b, w1b, ws);
  gcnn_critic_kernel<<<512, 256, SMEM_TOTAL, stream>>>(
      obs, act, b0a, b1a, w2a, b2a, b0b, b1b, w2b, b2b, ws, (float*)d_out);
}